// Round 3
// baseline (2621.501 us; speedup 1.0000x reference)
//
#include <hip/hip_runtime.h>

// ChainMessagePassing: out[n] = sum over edges with dst==n of x[src], over two edge lists.
// x: [N=100000, 64] fp32; indices: [2, E=3200000] (src row 0, dst row 1), int64 or int32.
//
// R3 strategy: coarse bucket sort (NPB=64 nodes/bucket) + LDS-accumulated gather.
// R2's per-node counting sort wrote 386 MB of dirty lines scattering 4B ids to
// random cursors; coarse buckets let blocks reserve contiguous runs (coalesced
// writes) and the gather block accumulates 64 node rows in 16 KB LDS with
// ds_add_f32 (no global data atomics at all).

static constexpr int D = 64;
static constexpr int Q = 16;          // float4 quads per row
static constexpr int NPB = 64;        // nodes per bucket
static constexpr int NPB_SHIFT = 6;
static constexpr int CHUNK = 16384;   // edges per scatter block

// ---- index dtype sniffer: int64 nonneg <2^31 has all-zero odd dwords ----
__global__ void detect_idx_dtype(const int* __restrict__ w, int* __restrict__ flag) {
    int tid = threadIdx.x;  // one wave
    int v = w[2 * tid + 1];
    unsigned long long m = __ballot(v != 0);
    if (tid == 0) *flag = (m == 0ULL) ? 1 : 0;
}

__device__ __forceinline__ int load_idx(const void* idx, long long i, int is64) {
    return is64 ? (int)((const long long*)idx)[i] : ((const int*)idx)[i];
}

// ---- phase 1: bucket histogram, LDS-aggregated ----
__global__ __launch_bounds__(256) void bucket_hist_kernel(
        const void* __restrict__ up, const void* __restrict__ down,
        int* __restrict__ bcounts, const int* __restrict__ flag, int E, int NB) {
    extern __shared__ int lcnt[];
    const int is64 = *flag;
    for (int i = threadIdx.x; i < NB; i += blockDim.x) lcnt[i] = 0;
    __syncthreads();
    const long long total = 2LL * E;
    const long long stride = (long long)gridDim.x * blockDim.x;
    for (long long e = (long long)blockIdx.x * blockDim.x + threadIdx.x;
         e < total; e += stride) {
        const void* idx = up; long long ee = e;
        if (ee >= E) { idx = down; ee -= E; }
        int dst = load_idx(idx, E + ee, is64);
        atomicAdd(&lcnt[dst >> NPB_SHIFT], 1);
    }
    __syncthreads();
    for (int i = threadIdx.x; i < NB; i += blockDim.x)
        if (lcnt[i]) atomicAdd(&bcounts[i], lcnt[i]);
}

// ---- phase 2: exclusive scan over NB buckets, one block ----
__global__ __launch_bounds__(1024) void scan_kernel(
        const int* __restrict__ counts, int* __restrict__ offsets,
        int* __restrict__ cursors, int NB) {
    __shared__ int sums[1024];
    const int tid = threadIdx.x;
    const int chunk = (NB + 1023) / 1024;
    const int start = tid * chunk;
    const int end = min(start + chunk, NB);
    int s = 0;
    for (int i = start; i < end; i++) s += counts[i];
    sums[tid] = s;
    __syncthreads();
    for (int off = 1; off < 1024; off <<= 1) {
        int t = (tid >= off) ? sums[tid - off] : 0;
        __syncthreads();
        sums[tid] += t;
        __syncthreads();
    }
    int run = (tid == 0) ? 0 : sums[tid - 1];
    for (int i = start; i < end; i++) {
        offsets[i] = run;
        cursors[i] = run;
        run += counts[i];
    }
    if (tid == 1023) offsets[NB] = run;
}

// ---- phase 3: scatter packed (src<<6 | dst&63) into bucket bins ----
// Per-block two-pass: count chunk per bucket, reserve contiguous runs with one
// global atomic per (block,bucket), then write runs (coalesced-ish).
__global__ __launch_bounds__(256) void bucket_scatter_kernel(
        const void* __restrict__ up, const void* __restrict__ down,
        int* __restrict__ gcursor, unsigned* __restrict__ packed,
        const int* __restrict__ flag, int E, int NB) {
    extern __shared__ int lds[];
    int* cnt = lds;        // [NB]
    int* base = lds + NB;  // [NB]
    const int is64 = *flag;
    const long long total = 2LL * E;
    const long long cs = (long long)blockIdx.x * CHUNK;
    if (cs >= total) return;
    const long long ce = min(total, cs + (long long)CHUNK);

    for (int i = threadIdx.x; i < NB; i += blockDim.x) cnt[i] = 0;
    __syncthreads();
    for (long long e = cs + threadIdx.x; e < ce; e += blockDim.x) {
        const void* idx = up; long long ee = e;
        if (ee >= E) { idx = down; ee -= E; }
        int dst = load_idx(idx, E + ee, is64);
        atomicAdd(&cnt[dst >> NPB_SHIFT], 1);
    }
    __syncthreads();
    for (int i = threadIdx.x; i < NB; i += blockDim.x) {
        int c = cnt[i];
        base[i] = c ? atomicAdd(&gcursor[i], c) : 0;
        cnt[i] = 0;  // reuse as local cursor
    }
    __syncthreads();
    for (long long e = cs + threadIdx.x; e < ce; e += blockDim.x) {
        const void* idx = up; long long ee = e;
        if (ee >= E) { idx = down; ee -= E; }
        int src = load_idx(idx, ee, is64);
        int dst = load_idx(idx, E + ee, is64);
        int b = dst >> NPB_SHIFT;
        int pos = base[b] + atomicAdd(&cnt[b], 1);
        packed[pos] = ((unsigned)src << NPB_SHIFT) | (unsigned)(dst & (NPB - 1));
    }
}

// ---- phase 4: per-bucket gather + LDS fp32 accumulate, no global atomics ----
// Component slot rotated by (dl&3) to spread ds_add_f32 across all 32 banks.
__device__ __forceinline__ void lds_add_rot(float* accrow, int r, float4 v) {
    float a0 = v.x, a1 = v.y, a2 = v.z, a3 = v.w, t;
    if (r & 1) { t = a3; a3 = a2; a2 = a1; a1 = a0; a0 = t; }   // rotate right 1
    if (r & 2) { t = a0; a0 = a2; a2 = t; t = a1; a1 = a3; a3 = t; }  // rotate 2
    atomicAdd(accrow + 0, a0);
    atomicAdd(accrow + 1, a1);
    atomicAdd(accrow + 2, a2);
    atomicAdd(accrow + 3, a3);
}

__global__ __launch_bounds__(256) void bucket_gather_kernel(
        const float* __restrict__ x, const int* __restrict__ offsets,
        const unsigned* __restrict__ packed, float* __restrict__ out, int N) {
    __shared__ float acc[NPB * D];  // 16 KB
    const int b = blockIdx.x;
    const int tid = threadIdx.x;
    float4* acc4 = (float4*)acc;
    for (int i = tid; i < NPB * D / 4; i += blockDim.x)
        acc4[i] = make_float4(0.f, 0.f, 0.f, 0.f);
    __syncthreads();

    const int beg = offsets[b], end = offsets[b + 1];
    const int g = tid >> 4;   // edge group 0..15
    const int q = tid & 15;   // quad within row
    int e = beg + g;
    for (; e + 48 < end; e += 64) {  // 4 edges in flight per group
        unsigned p0 = packed[e], p1 = packed[e + 16], p2 = packed[e + 32], p3 = packed[e + 48];
        const float4 v0 = *(const float4*)(x + ((long long)(p0 >> NPB_SHIFT)) * D + q * 4);
        const float4 v1 = *(const float4*)(x + ((long long)(p1 >> NPB_SHIFT)) * D + q * 4);
        const float4 v2 = *(const float4*)(x + ((long long)(p2 >> NPB_SHIFT)) * D + q * 4);
        const float4 v3 = *(const float4*)(x + ((long long)(p3 >> NPB_SHIFT)) * D + q * 4);
        int d0 = p0 & (NPB - 1), d1 = p1 & (NPB - 1), d2 = p2 & (NPB - 1), d3 = p3 & (NPB - 1);
        lds_add_rot(acc + d0 * D + q * 4, d0 & 3, v0);
        lds_add_rot(acc + d1 * D + q * 4, d1 & 3, v1);
        lds_add_rot(acc + d2 * D + q * 4, d2 & 3, v2);
        lds_add_rot(acc + d3 * D + q * 4, d3 & 3, v3);
    }
    for (; e < end; e += 16) {
        unsigned p = packed[e];
        const float4 v = *(const float4*)(x + ((long long)(p >> NPB_SHIFT)) * D + q * 4);
        int dl = p & (NPB - 1);
        lds_add_rot(acc + dl * D + q * 4, dl & 3, v);
    }
    __syncthreads();

    const int node0 = b * NPB;
    const int nquads = min(NPB, N - node0) * Q;
    for (int i = tid; i < nquads; i += blockDim.x) {
        const int dl = i >> 4;
        const int qb = i * 4;  // quad base dword
        float4 w;
        w.x = acc[qb + ((0 + dl) & 3)];
        w.y = acc[qb + ((1 + dl) & 3)];
        w.z = acc[qb + ((2 + dl) & 3)];
        w.w = acc[qb + ((3 + dl) & 3)];
        *(float4*)(out + (long long)node0 * D + (long long)i * 4) = w;
    }
}

// ---- fallback: direct fp32 atomics (R1), needs no workspace ----
__global__ __launch_bounds__(256) void scatter_add_kernel(
        const float* __restrict__ x, const void* __restrict__ up_idx,
        const void* __restrict__ down_idx, float* __restrict__ out,
        const int* __restrict__ dtype_flag, int num_edges) {
    const int is64 = *dtype_flag;
    const long long total = 2LL * num_edges * Q;
    const long long stride = (long long)gridDim.x * blockDim.x;
    for (long long t = (long long)blockIdx.x * blockDim.x + threadIdx.x;
         t < total; t += stride) {
        const int quad = (int)(t & (Q - 1));
        long long eg = t >> 4;
        const void* idx = up_idx;
        if (eg >= num_edges) { idx = down_idx; eg -= num_edges; }
        int src = load_idx(idx, eg, is64);
        int dst = load_idx(idx, num_edges + eg, is64);
        const float4 v = *(const float4*)(x + (long long)src * D + quad * 4);
        float* o = out + (long long)dst * D + quad * 4;
        unsafeAtomicAdd(o + 0, v.x);
        unsafeAtomicAdd(o + 1, v.y);
        unsafeAtomicAdd(o + 2, v.z);
        unsafeAtomicAdd(o + 3, v.w);
    }
}

extern "C" void kernel_launch(void* const* d_in, const int* in_sizes, int n_in,
                              void* d_out, int out_size, void* d_ws, size_t ws_size,
                              hipStream_t stream) {
    const float* x = (const float*)d_in[0];
    const void* up_idx = d_in[1];
    const void* down_idx = d_in[2];
    float* out = (float*)d_out;

    const int E = in_sizes[1] / 2;   // [2, E]
    const int N = out_size / D;      // [N, 64]
    const int NB = (N + NPB - 1) / NPB;
    const long long Etot = 2LL * E;

    // ws layout (ints): flag(64) | counts[NB] | offsets[NB+1] pad | cursors[NB] | packed[2E]
    int* ws_i = (int*)d_ws;
    int* flag = ws_i;
    int* counts = ws_i + 64;
    int* offsets = counts + NB;
    int* cursors = offsets + NB + 15;
    unsigned* packed = (unsigned*)(cursors + NB);
    const size_t ws_need = (size_t)(64 + 3LL * NB + 16 + Etot) * 4 + 64;

    detect_idx_dtype<<<1, 64, 0, stream>>>((const int*)up_idx, flag);

    if (ws_size >= ws_need && N <= (1 << 25) && Etot < (1LL << 31)) {
        hipMemsetAsync(counts, 0, (size_t)NB * sizeof(int), stream);
        bucket_hist_kernel<<<512, 256, NB * sizeof(int), stream>>>(
            up_idx, down_idx, counts, flag, E, NB);
        scan_kernel<<<1, 1024, 0, stream>>>(counts, offsets, cursors, NB);
        const int sblocks = (int)((Etot + CHUNK - 1) / CHUNK);
        bucket_scatter_kernel<<<sblocks, 256, 2 * NB * sizeof(int), stream>>>(
            up_idx, down_idx, cursors, packed, flag, E, NB);
        bucket_gather_kernel<<<NB, 256, 0, stream>>>(x, offsets, packed, out, N);
    } else {
        hipMemsetAsync(d_out, 0, (size_t)out_size * sizeof(float), stream);
        scatter_add_kernel<<<8192, 256, 0, stream>>>(x, up_idx, down_idx, out, flag, E);
    }
}

// Round 4
// 479.924 us; speedup vs baseline: 5.4623x; 5.4623x over previous
//
#include <hip/hip_runtime.h>

// ChainMessagePassing: out[n] = sum over edges with dst==n of x[src], over two edge lists.
// x: [N=100000, 64] fp32; indices: [2, E=3200000] (src row 0, dst row 1), int64 or int32.
//
// R4: coarse bucket sort (NPB=64 nodes/bucket) + per-bucket LDS counting sort
// + ATOMIC-FREE register-accumulated gather. R3's 409.6M ds_add_f32 atomics
// (64 lane-atomics/edge) saturated the DS pipe at 2.35 ms; sorting each
// bucket's edges by local dst costs ~4 LDS wave-ops/edge and lets 16-lane
// groups accumulate whole node rows in VGPRs.

static constexpr int D = 64;
static constexpr int Q = 16;          // float4 quads per row
static constexpr int NPB = 64;        // nodes per bucket
static constexpr int NPB_SHIFT = 6;
static constexpr int CHUNK = 16384;   // edges per scatter block
static constexpr int CH = 4096;       // edges per gather sort chunk (16 KB LDS)

// ---- index dtype sniffer: int64 nonneg <2^31 has all-zero odd dwords ----
__global__ void detect_idx_dtype(const int* __restrict__ w, int* __restrict__ flag) {
    int tid = threadIdx.x;  // one wave
    int v = w[2 * tid + 1];
    unsigned long long m = __ballot(v != 0);
    if (tid == 0) *flag = (m == 0ULL) ? 1 : 0;
}

__device__ __forceinline__ int load_idx(const void* idx, long long i, int is64) {
    return is64 ? (int)((const long long*)idx)[i] : ((const int*)idx)[i];
}

// ---- phase 1: bucket histogram, LDS-aggregated ----
__global__ __launch_bounds__(256) void bucket_hist_kernel(
        const void* __restrict__ up, const void* __restrict__ down,
        int* __restrict__ bcounts, const int* __restrict__ flag, int E, int NB) {
    extern __shared__ int lcnt[];
    const int is64 = *flag;
    for (int i = threadIdx.x; i < NB; i += blockDim.x) lcnt[i] = 0;
    __syncthreads();
    const long long total = 2LL * E;
    const long long stride = (long long)gridDim.x * blockDim.x;
    for (long long e = (long long)blockIdx.x * blockDim.x + threadIdx.x;
         e < total; e += stride) {
        const void* idx = up; long long ee = e;
        if (ee >= E) { idx = down; ee -= E; }
        int dst = load_idx(idx, E + ee, is64);
        atomicAdd(&lcnt[dst >> NPB_SHIFT], 1);
    }
    __syncthreads();
    for (int i = threadIdx.x; i < NB; i += blockDim.x)
        if (lcnt[i]) atomicAdd(&bcounts[i], lcnt[i]);
}

// ---- phase 2: exclusive scan over NB buckets, one block ----
__global__ __launch_bounds__(1024) void scan_kernel(
        const int* __restrict__ counts, int* __restrict__ offsets,
        int* __restrict__ cursors, int NB) {
    __shared__ int sums[1024];
    const int tid = threadIdx.x;
    const int chunk = (NB + 1023) / 1024;
    const int start = tid * chunk;
    const int end = min(start + chunk, NB);
    int s = 0;
    for (int i = start; i < end; i++) s += counts[i];
    sums[tid] = s;
    __syncthreads();
    for (int off = 1; off < 1024; off <<= 1) {
        int t = (tid >= off) ? sums[tid - off] : 0;
        __syncthreads();
        sums[tid] += t;
        __syncthreads();
    }
    int run = (tid == 0) ? 0 : sums[tid - 1];
    for (int i = start; i < end; i++) {
        offsets[i] = run;
        cursors[i] = run;
        run += counts[i];
    }
    if (tid == 1023) offsets[NB] = run;
}

// ---- phase 3: scatter packed (src<<6 | dst&63) into bucket bins ----
__global__ __launch_bounds__(256) void bucket_scatter_kernel(
        const void* __restrict__ up, const void* __restrict__ down,
        int* __restrict__ gcursor, unsigned* __restrict__ packed,
        const int* __restrict__ flag, int E, int NB) {
    extern __shared__ int lds[];
    int* cnt = lds;        // [NB]
    int* base = lds + NB;  // [NB]
    const int is64 = *flag;
    const long long total = 2LL * E;
    const long long cs = (long long)blockIdx.x * CHUNK;
    if (cs >= total) return;
    const long long ce = min(total, cs + (long long)CHUNK);

    for (int i = threadIdx.x; i < NB; i += blockDim.x) cnt[i] = 0;
    __syncthreads();
    for (long long e = cs + threadIdx.x; e < ce; e += blockDim.x) {
        const void* idx = up; long long ee = e;
        if (ee >= E) { idx = down; ee -= E; }
        int dst = load_idx(idx, E + ee, is64);
        atomicAdd(&cnt[dst >> NPB_SHIFT], 1);
    }
    __syncthreads();
    for (int i = threadIdx.x; i < NB; i += blockDim.x) {
        int c = cnt[i];
        base[i] = c ? atomicAdd(&gcursor[i], c) : 0;
        cnt[i] = 0;  // reuse as local cursor
    }
    __syncthreads();
    for (long long e = cs + threadIdx.x; e < ce; e += blockDim.x) {
        const void* idx = up; long long ee = e;
        if (ee >= E) { idx = down; ee -= E; }
        int src = load_idx(idx, ee, is64);
        int dst = load_idx(idx, E + ee, is64);
        int b = dst >> NPB_SHIFT;
        int pos = base[b] + atomicAdd(&cnt[b], 1);
        packed[pos] = ((unsigned)src << NPB_SHIFT) | (unsigned)(dst & (NPB - 1));
    }
}

// ---- phase 4: per-bucket counting sort + atomic-free register gather ----
// Group g (16 lanes) owns local nodes 4g..4g+3; accumulates float4 quads in
// VGPRs over each node's sorted edge run. Edge runs come from a per-chunk
// 64-key counting sort in LDS.
__global__ __launch_bounds__(256) void bucket_gather_kernel(
        const float* __restrict__ x, const int* __restrict__ offsets,
        const unsigned* __restrict__ packed, float* __restrict__ out, int N) {
    __shared__ unsigned sorted[CH];     // 16 KB
    __shared__ int cnt[NPB];
    __shared__ int binoff[NPB + 1];
    __shared__ int cursor[NPB];

    const int b = blockIdx.x;
    const int tid = threadIdx.x;
    const int g = tid >> 4;   // group 0..15
    const int q = tid & 15;   // quad within row
    const int beg = offsets[b], end = offsets[b + 1];

    float4 acc[4];
    acc[0] = acc[1] = acc[2] = acc[3] = make_float4(0.f, 0.f, 0.f, 0.f);

    for (int cs = beg; cs < end; cs += CH) {
        const int m = min(CH, end - cs);
        for (int i = tid; i < NPB; i += 256) cnt[i] = 0;
        __syncthreads();
        for (int i = tid; i < m; i += 256)
            atomicAdd(&cnt[packed[cs + i] & (NPB - 1)], 1);
        __syncthreads();
        if (tid < NPB) {  // wave 0: inclusive scan over 64 bins via shfl
            int v = cnt[tid];
            int inc = v;
            #pragma unroll
            for (int off = 1; off < 64; off <<= 1) {
                int t = __shfl_up(inc, off, 64);
                if (tid >= off) inc += t;
            }
            binoff[tid + 1] = inc;
            cursor[tid] = inc - v;  // exclusive
            if (tid == 0) binoff[0] = 0;
        }
        __syncthreads();
        for (int i = tid; i < m; i += 256) {
            unsigned p = packed[cs + i];
            int pos = atomicAdd(&cursor[p & (NPB - 1)], 1);
            sorted[pos] = p;
        }
        __syncthreads();
        #pragma unroll
        for (int j = 0; j < 4; j++) {
            const int dl = 4 * g + j;
            const int rb = binoff[dl], re = binoff[dl + 1];
            int e = rb;
            for (; e + 3 < re; e += 4) {  // 4 row-gathers in flight
                unsigned p0 = sorted[e], p1 = sorted[e + 1];
                unsigned p2 = sorted[e + 2], p3 = sorted[e + 3];
                const float4 v0 = *(const float4*)(x + ((long long)(p0 >> NPB_SHIFT)) * D + q * 4);
                const float4 v1 = *(const float4*)(x + ((long long)(p1 >> NPB_SHIFT)) * D + q * 4);
                const float4 v2 = *(const float4*)(x + ((long long)(p2 >> NPB_SHIFT)) * D + q * 4);
                const float4 v3 = *(const float4*)(x + ((long long)(p3 >> NPB_SHIFT)) * D + q * 4);
                acc[j].x += (v0.x + v1.x) + (v2.x + v3.x);
                acc[j].y += (v0.y + v1.y) + (v2.y + v3.y);
                acc[j].z += (v0.z + v1.z) + (v2.z + v3.z);
                acc[j].w += (v0.w + v1.w) + (v2.w + v3.w);
            }
            for (; e < re; e++) {
                unsigned p = sorted[e];
                const float4 v = *(const float4*)(x + ((long long)(p >> NPB_SHIFT)) * D + q * 4);
                acc[j].x += v.x; acc[j].y += v.y; acc[j].z += v.z; acc[j].w += v.w;
            }
        }
        __syncthreads();  // gather reads done before next chunk reuses LDS
    }

    const int node0 = b * NPB;
    #pragma unroll
    for (int j = 0; j < 4; j++) {
        const int node = node0 + 4 * g + j;
        if (node < N)
            *(float4*)(out + (long long)node * D + q * 4) = acc[j];
    }
}

// ---- fallback: direct fp32 atomics (R1), needs no workspace ----
__global__ __launch_bounds__(256) void scatter_add_kernel(
        const float* __restrict__ x, const void* __restrict__ up_idx,
        const void* __restrict__ down_idx, float* __restrict__ out,
        const int* __restrict__ dtype_flag, int num_edges) {
    const int is64 = *dtype_flag;
    const long long total = 2LL * num_edges * Q;
    const long long stride = (long long)gridDim.x * blockDim.x;
    for (long long t = (long long)blockIdx.x * blockDim.x + threadIdx.x;
         t < total; t += stride) {
        const int quad = (int)(t & (Q - 1));
        long long eg = t >> 4;
        const void* idx = up_idx;
        if (eg >= num_edges) { idx = down_idx; eg -= num_edges; }
        int src = load_idx(idx, eg, is64);
        int dst = load_idx(idx, num_edges + eg, is64);
        const float4 v = *(const float4*)(x + (long long)src * D + quad * 4);
        float* o = out + (long long)dst * D + quad * 4;
        unsafeAtomicAdd(o + 0, v.x);
        unsafeAtomicAdd(o + 1, v.y);
        unsafeAtomicAdd(o + 2, v.z);
        unsafeAtomicAdd(o + 3, v.w);
    }
}

extern "C" void kernel_launch(void* const* d_in, const int* in_sizes, int n_in,
                              void* d_out, int out_size, void* d_ws, size_t ws_size,
                              hipStream_t stream) {
    const float* x = (const float*)d_in[0];
    const void* up_idx = d_in[1];
    const void* down_idx = d_in[2];
    float* out = (float*)d_out;

    const int E = in_sizes[1] / 2;   // [2, E]
    const int N = out_size / D;      // [N, 64]
    const int NB = (N + NPB - 1) / NPB;
    const long long Etot = 2LL * E;

    // ws layout (ints): flag(64) | counts[NB] | offsets[NB+1] pad | cursors[NB] | packed[2E]
    int* ws_i = (int*)d_ws;
    int* flag = ws_i;
    int* counts = ws_i + 64;
    int* offsets = counts + NB;
    int* cursors = offsets + NB + 15;
    unsigned* packed = (unsigned*)(cursors + NB);
    const size_t ws_need = (size_t)(64 + 3LL * NB + 16 + Etot) * 4 + 64;

    detect_idx_dtype<<<1, 64, 0, stream>>>((const int*)up_idx, flag);

    if (ws_size >= ws_need && N <= (1 << 25) && Etot < (1LL << 31)) {
        hipMemsetAsync(counts, 0, (size_t)NB * sizeof(int), stream);
        bucket_hist_kernel<<<512, 256, NB * sizeof(int), stream>>>(
            up_idx, down_idx, counts, flag, E, NB);
        scan_kernel<<<1, 1024, 0, stream>>>(counts, offsets, cursors, NB);
        const int sblocks = (int)((Etot + CHUNK - 1) / CHUNK);
        bucket_scatter_kernel<<<sblocks, 256, 2 * NB * sizeof(int), stream>>>(
            up_idx, down_idx, cursors, packed, flag, E, NB);
        bucket_gather_kernel<<<NB, 256, 0, stream>>>(x, offsets, packed, out, N);
    } else {
        hipMemsetAsync(d_out, 0, (size_t)out_size * sizeof(float), stream);
        scatter_add_kernel<<<8192, 256, 0, stream>>>(x, up_idx, down_idx, out, flag, E);
    }
}